// Round 10
// baseline (714.238 us; speedup 1.0000x reference)
//
#include <hip/hip_runtime.h>
#include <hip/hip_bf16.h>

#define NN 8192
#define DIM 128
#define BM 16
#define BK 64
#define NT (NN / BK)

typedef __attribute__((ext_vector_type(4))) float f32x4;
typedef __attribute__((ext_vector_type(8))) short bf16x8;
typedef __attribute__((ext_vector_type(4))) short bf16x4;

static __device__ __forceinline__ short f2bf(float f) {
    __hip_bfloat16 h = __float2bfloat16(f);
    return *reinterpret_cast<short*>(&h);
}
static __device__ __forceinline__ float bf2f(short s) {
    union { unsigned int u; float f; } c;
    c.u = ((unsigned int)(unsigned short)s) << 16;
    return c.f;
}
static __device__ __forceinline__ bf16x8 cvt8(float4 a, float4 b) {
    bf16x8 r;
    r[0] = f2bf(a.x); r[1] = f2bf(a.y); r[2] = f2bf(a.z); r[3] = f2bf(a.w);
    r[4] = f2bf(b.x); r[5] = f2bf(b.y); r[6] = f2bf(b.z); r[7] = f2bf(b.w);
    return r;
}

// ---------------- kernel 1: degree row-sums -> d^{-1/2} ----------------
__global__ __launch_bounds__(256) void k_rowsum(const float* __restrict__ A,
                                                float* __restrict__ dinv) {
    const int row = blockIdx.x;
    const int t = threadIdx.x;
    const float4* a4 = reinterpret_cast<const float4*>(A + (size_t)row * NN);
    float s = 0.f;
#pragma unroll
    for (int q = 0; q < 8; ++q) {
        float4 v = a4[q * 256 + t];
        s += (v.x + v.y) + (v.z + v.w);
    }
#pragma unroll
    for (int off = 32; off > 0; off >>= 1) s += __shfl_down(s, off);
    __shared__ float red[4];
    if ((t & 63) == 0) red[t >> 6] = s;
    __syncthreads();
    if (t == 0) {
        float deg = red[0] + red[1] + red[2] + red[3] + 1.0f;   // +I self-loop
        dinv[row] = 1.0f / sqrtf(deg);
    }
}

// ------- kernel 2: Yt[f'][j] = bf16( dinv[j] * sum_f X[j][f] * W[f'][f] ) -------
__global__ __launch_bounds__(256) void k_y(const float* __restrict__ X,
                                           const float* __restrict__ W,
                                           const float* __restrict__ dinv,
                                           short* __restrict__ Yt) {
    __shared__ float Wl[64 * 128];
    __shared__ float Xl[32 * 129];   // +1 pad: conflict-free lane=j reads
    const int t = threadIdx.x;
    const int j0 = (blockIdx.x >> 1) * 32;
    const int half = blockIdx.x & 1;

    const float4* wg = reinterpret_cast<const float4*>(W + (size_t)half * 64 * 128);
#pragma unroll
    for (int q = 0; q < 8; ++q)
        reinterpret_cast<float4*>(Wl)[q * 256 + t] = wg[q * 256 + t];
#pragma unroll
    for (int q = 0; q < 4; ++q) {
        int p = q * 256 + t;
        int row = p >> 5, c4 = p & 31;
        float4 v = reinterpret_cast<const float4*>(X + (size_t)(j0 + row) * DIM)[c4];
        float* dst = Xl + row * 129 + c4 * 4;
        dst[0] = v.x; dst[1] = v.y; dst[2] = v.z; dst[3] = v.w;
    }
    __syncthreads();

    const int j = t & 31;
    const int fb = t >> 5;             // 0..7
    const float dj = dinv[j0 + j];
    float acc[8];
#pragma unroll
    for (int k = 0; k < 8; ++k) acc[k] = 0.f;
    for (int f = 0; f < DIM; ++f) {
        float xv = Xl[j * 129 + f];
#pragma unroll
        for (int k = 0; k < 8; ++k)
            acc[k] = fmaf(xv, Wl[(fb + k * 8) * 128 + f], acc[k]);
    }
#pragma unroll
    for (int k = 0; k < 8; ++k)
        Yt[(size_t)(half * 64 + fb + k * 8) * NN + j0 + j] = f2bf(dj * acc[k]);
}

// ---------------- kernel 3: out = dinv[i]*( (A @ Y)[i,f] + Y[i,f] ) + b[f] ----------------
// LDS-free, barrier-free: each wave owns one 16x16 output tile; A and Yt fragments are
// loaded straight to registers (Yt is L2-resident; A is read once from HBM, 8-way
// intra-block reuse served by L1). Pure register dataflow -> compiler software-pipelines
// the loads across K iterations; no per-iter vmcnt(0) drain. Light barrier every 8 iters
// only to bound wave slip to ~one L1 (32 KB) of shared A-tile.
__global__ __launch_bounds__(512) void k_main(const float* __restrict__ A,
                                              const short* __restrict__ Yt,
                                              const float* __restrict__ dinv,
                                              const float* __restrict__ bias,
                                              float* __restrict__ out) {
    const int t = threadIdx.x;
    const int i0 = blockIdx.x * BM;
    const int lane = t & 63;
    const int wid = t >> 6;                // 0..7 = wave's 16-col group of Yt rows
    const int l15 = lane & 15, lk = lane >> 4;
    const int f = wid * 16 + l15;

    // fragment base pointers (per lane):
    //   A frag[kc][e] = A[i0+l15][kt*64 + kc*32 + lk*8 + e]   (f32, cvt to bf16)
    //   B frag[kc][e] = Yt[f]    [kt*64 + kc*32 + lk*8 + e]   (bf16)
    const float* aR = A + (size_t)(i0 + l15) * NN + lk * 8;
    const short* yR = Yt + (size_t)f * NN + lk * 8;

    f32x4 acc = {0.f, 0.f, 0.f, 0.f};

    // prologue: load tile 0
    float4 a0l = *reinterpret_cast<const float4*>(aR);
    float4 a0h = *reinterpret_cast<const float4*>(aR + 4);
    float4 a1l = *reinterpret_cast<const float4*>(aR + 32);
    float4 a1h = *reinterpret_cast<const float4*>(aR + 36);
    bf16x8 y0 = *reinterpret_cast<const bf16x8*>(yR);
    bf16x8 y1 = *reinterpret_cast<const bf16x8*>(yR + 32);

#pragma unroll 2
    for (int kt = 0; kt < NT; ++kt) {
        const int nb = (kt + 1 < NT ? kt + 1 : kt) * BK;   // next-tile element offset

        // prefetch next tile into registers (compiler pipelines these)
        float4 na0l = *reinterpret_cast<const float4*>(aR + nb);
        float4 na0h = *reinterpret_cast<const float4*>(aR + nb + 4);
        float4 na1l = *reinterpret_cast<const float4*>(aR + nb + 32);
        float4 na1h = *reinterpret_cast<const float4*>(aR + nb + 36);
        bf16x8 ny0 = *reinterpret_cast<const bf16x8*>(yR + nb);
        bf16x8 ny1 = *reinterpret_cast<const bf16x8*>(yR + nb + 32);

        // compute current tile (A cvt in-register, no LDS)
        acc = __builtin_amdgcn_mfma_f32_16x16x32_bf16(cvt8(a0l, a0h), y0, acc, 0, 0, 0);
        acc = __builtin_amdgcn_mfma_f32_16x16x32_bf16(cvt8(a1l, a1h), y1, acc, 0, 0, 0);

        a0l = na0l; a0h = na0h; a1l = na1l; a1h = na1h;
        y0 = ny0; y1 = ny1;

        // bound inter-wave slip so the shared A tile stays L1-resident
        if ((kt & 7) == 7) __syncthreads();
    }

    // ---- epilogue: out[i][f] = dinv[i]*(acc + Y[i][f]) + b[f] ----
    const int iBase = i0 + lk * 4;
    const float4 dv4 = *reinterpret_cast<const float4*>(dinv + iBase);
    const float dvr[4] = { dv4.x, dv4.y, dv4.z, dv4.w };
    const float bf_ = bias[f];
    bf16x4 yv = *reinterpret_cast<const bf16x4*>(Yt + (size_t)f * NN + iBase);
#pragma unroll
    for (int r = 0; r < 4; ++r) {
        float z = acc[r] + bf2f(yv[r]);
        out[(size_t)(iBase + r) * DIM + f] = dvr[r] * z + bf_;
    }
}

extern "C" void kernel_launch(void* const* d_in, const int* in_sizes, int n_in,
                              void* d_out, int out_size, void* d_ws, size_t ws_size,
                              hipStream_t stream) {
    (void)in_sizes; (void)n_in; (void)out_size; (void)ws_size;
    const float* X = (const float*)d_in[0];
    const float* A = (const float*)d_in[1];
    const float* W = (const float*)d_in[2];
    const float* b = (const float*)d_in[3];
    float* out = (float*)d_out;

    float* dinv = (float*)d_ws;                                  // 8192 f32
    short* Yt = (short*)((char*)d_ws + NN * sizeof(float));      // [128][8192] bf16

    k_rowsum<<<NN, 256, 0, stream>>>(A, dinv);
    k_y<<<(NN / 32) * 2, 256, 0, stream>>>(X, W, dinv, Yt);
    k_main<<<NN / BM, 512, 0, stream>>>(A, Yt, dinv, b, out);
}